// Round 8
// baseline (207.056 us; speedup 1.0000x reference)
//
#include <hip/hip_runtime.h>
#include <stdint.h>

// VectorQuantizer on MI355X (gfx950), fp32 exact path, round 8.
// R4-R7 all plateau at 47-64% VALUBusy: scalar K$ thrash puts every s_load
// batch at L2 latency (~200cy) and OOO SMEM forces lgkmcnt(0) drains; drain
// period = FMA work per prefetched scalar byte. Fix: P=4 points/lane
// (acc[4][16]) -> one 16-float w row feeds 64 FMA (128cy) instead of 32;
// SGPR prefetch now covers ~512cy/drain. Block = 8 waves x disjoint 64-code
// slices over the same 256 points -> all 512 codes in-block (LDS merge,
// fused epilogue, one loss atomic per block). 256 blocks x 512 thr.

#define DDIM 64
#define KCODES 512

// ws: wT 131072 B @ 0, wsq 2048 B @ 131072

__global__ void vq_prep(const float* __restrict__ w, float* __restrict__ wT,
                        float* __restrict__ wsq, float* __restrict__ loss_out) {
  int g = blockIdx.x * 256 + threadIdx.x;  // 128 blocks over D*K
  int d = g >> 9, k = g & 511;
  wT[k * DDIM + d] = w[g];                 // [K][D] for epilogue gather
  if (g < KCODES) {
    float s = 0.f;
    for (int dd = 0; dd < DDIM; ++dd) {
      float t = w[dd * KCODES + g];
      s = fmaf(t, t, s);
    }
    wsq[g] = s;
  }
  if (g == 0) *loss_out = 0.f;             // d_out is poisoned each launch
}

__global__ __launch_bounds__(512, 4)
void vq_main(const float* __restrict__ x_in, const float* __restrict__ w,
             const float* __restrict__ wT, const float* __restrict__ wsq,
             float* __restrict__ out_q, float* __restrict__ out_idx,
             float* __restrict__ loss_out) {
  __shared__ unsigned long long sm_key[8][256];  // per-wave candidate keys
  __shared__ unsigned int sm_idx[256];
  __shared__ float sm_sx[256];
  __shared__ float sm_loss[256];

  const int t = threadIdx.x;
  const int pb = blockIdx.x;                              // 256 blocks, 256 pts
  const int wv = __builtin_amdgcn_readfirstlane(t >> 6);  // wave id 0..7 (SGPR)
  const int lane = t & 63;

  // 4 points per lane, interleaved: p_j = pb*256 + j*64 + lane
  const float* xp[4];
#pragma unroll
  for (int j = 0; j < 4; ++j)
    xp[j] = x_in + (((size_t)pb << 8) + (j << 6) + lane) * DDIM;

  float best[4] = {3.0e38f, 3.0e38f, 3.0e38f, 3.0e38f};
  int bi[4] = {0, 0, 0, 0};
  float sx[4] = {0.f, 0.f, 0.f, 0.f};

#pragma unroll 1
  for (int kb = 0; kb < 4; ++kb) {
    const int k0 = (wv << 6) + (kb << 4);  // wave's 16-code window, ascending
    const float* wp = w + k0;              // SGPR-rooted -> s_load promotion
    float acc[4][16];
#pragma unroll
    for (int j = 0; j < 4; ++j)
#pragma unroll
      for (int c = 0; c < 16; ++c) acc[j][c] = 0.f;

#pragma unroll 1
    for (int d8 = 0; d8 < 8; ++d8) {
      float xv[4][8];
#pragma unroll
      for (int j = 0; j < 4; ++j) {
        float4 a = *(const float4*)(xp[j] + (d8 << 3));
        float4 b = *(const float4*)(xp[j] + (d8 << 3) + 4);
        xv[j][0] = a.x; xv[j][1] = a.y; xv[j][2] = a.z; xv[j][3] = a.w;
        xv[j][4] = b.x; xv[j][5] = b.y; xv[j][6] = b.z; xv[j][7] = b.w;
      }
      if (wv == 0 && kb == 0) {  // wave-uniform: ||x||^2 once per point
#pragma unroll
        for (int j = 0; j < 4; ++j)
#pragma unroll
          for (int dd = 0; dd < 8; ++dd)
            sx[j] = fmaf(xv[j][dd], xv[j][dd], sx[j]);
      }
#pragma unroll
      for (int dd = 0; dd < 8; ++dd) {
        const float* wd = wp + (((d8 << 3) + dd) << 9);  // w[d][k0..k0+15]
#pragma unroll
        for (int c = 0; c < 16; ++c) {
          float wvv = wd[c];               // wave-uniform -> SGPR operand
#pragma unroll
          for (int j = 0; j < 4; ++j)
            acc[j][c] = fmaf(wvv, xv[j][dd], acc[j][c]);
        }
      }
    }
#pragma unroll
    for (int c = 0; c < 16; ++c) {
      float wq = wsq[k0 + c];
#pragma unroll
      for (int j = 0; j < 4; ++j) {
        float dj = fmaf(acc[j][c], -2.0f, wq);
        if (dj < best[j]) { best[j] = dj; bi[j] = k0 + c; }  // strict <
      }
    }
  }

  // sortable-float pack, idx in low bits -> exact ties pick lowest index
#pragma unroll
  for (int j = 0; j < 4; ++j) {
    unsigned int u = __float_as_uint(best[j]);
    u = (u & 0x80000000u) ? ~u : (u | 0x80000000u);
    sm_key[wv][(j << 6) | lane] =
        ((unsigned long long)u << 32) | (unsigned long long)(unsigned int)bi[j];
  }
  if (wv == 0) {
#pragma unroll
    for (int j = 0; j < 4; ++j) sm_sx[(j << 6) | lane] = sx[j];
  }
  __syncthreads();

  // merge the 8 per-wave candidates for each of the 256 points
  if (t < 256) {
    unsigned long long k = sm_key[0][t];
#pragma unroll
    for (int wi = 1; wi < 8; ++wi) {
      unsigned long long k2 = sm_key[wi][t];
      k = k2 < k ? k2 : k;
    }
    unsigned int idx = (unsigned int)k;
    sm_idx[t] = idx;
    out_idx[((size_t)pb << 8) + t] = (float)idx;
    unsigned int u = (unsigned int)(k >> 32);
    u = (u & 0x80000000u) ? (u & 0x7FFFFFFFu) : ~u;
    // ||x-q||^2 = ||x||^2 + (||q||^2 - 2 x.q), pre-scaled by 1.25/(N*D)
    sm_loss[t] = (__uint_as_float(u) + sm_sx[t]) * (1.25f / 4194304.0f);
  }
  __syncthreads();

  // epilogue: gather code rows, coalesced 256x64 out tile (4096 float4)
  float4* dst = (float4*)(out_q + ((size_t)pb << 14));
#pragma unroll
  for (int i = 0; i < 8; ++i) {
    int e = i * 512 + t;
    int p2 = e >> 4, d4 = e & 15;
    unsigned int idx = sm_idx[p2];                            // LDS broadcast
    dst[e] = ((const float4*)(wT + (size_t)idx * DDIM))[d4];  // L2-hot
  }

  // block loss partial -> single atomic (256 adds total)
  if (t < 64) {
    float s = sm_loss[t] + sm_loss[t + 64] + sm_loss[t + 128] +
              sm_loss[t + 192];
#pragma unroll
    for (int off = 32; off > 0; off >>= 1) s += __shfl_down(s, off);
    if (t == 0) atomicAdd(loss_out, s);
  }
}

extern "C" void kernel_launch(void* const* d_in, const int* in_sizes, int n_in,
                              void* d_out, int out_size, void* d_ws, size_t ws_size,
                              hipStream_t stream) {
  const float* x = (const float*)d_in[0];  // (64,32,32,64) fp32
  const float* w = (const float*)d_in[1];  // (64,512) fp32

  char* ws = (char*)d_ws;
  float* wT = (float*)(ws);
  float* wsq = (float*)(ws + 131072);

  float* out_q = (float*)d_out;            // 4194304 floats
  float* out_idx = out_q + 4194304;        // 65536 floats (indices)
  float* loss_out = out_q + 4259840;       // 1 float

  vq_prep<<<128, 256, 0, stream>>>(w, wT, wsq, loss_out);
  vq_main<<<256, 512, 0, stream>>>(x, w, wT, wsq, out_q, out_idx, loss_out);
}

// Round 9
// 120.169 us; speedup vs baseline: 1.7230x; 1.7230x over previous
//
#include <hip/hip_runtime.h>
#include <stdint.h>

// VectorQuantizer on MI355X (gfx950), fp32 exact path, round 9.
// R8 post-mortem: P=4 spilled (VGPR cap 64, WRITE 92MB, 25% busy). Confirmed
// viable inner loop is R5/R6-shaped: P=1, acc[16..32], VGPR 20-36.
// R4-R7 plateau re-read: ~35us of VALU work at ~35% occupancy = only ~3
// resident waves/SIMD (grid 1024 x 4-wave blocks demands exactly 4/SIMD) --
// not enough TLP to hide s_load/x latency. This round: 8-wave blocks (512
// thr), 64 pts/block, each wave owns a 64-code slice (kb=2 x acc[32], R6's
// proven no-spill codegen), grid 1024 -> 32 waves/CU = 8/SIMD (hw max).
// x staged in LDS (R5 path), in-block 8-way key merge, fused epilogue.

#define DDIM 64
#define KCODES 512

// ws: wT 131072 B @ 0, wsq 2048 B @ 131072

__global__ void vq_prep(const float* __restrict__ w, float* __restrict__ wT,
                        float* __restrict__ wsq, float* __restrict__ loss_out) {
  int g = blockIdx.x * 256 + threadIdx.x;  // 128 blocks over D*K
  int d = g >> 9, k = g & 511;
  wT[k * DDIM + d] = w[g];                 // [K][D] for epilogue gather
  if (g < KCODES) {
    float s = 0.f;
    for (int dd = 0; dd < DDIM; ++dd) {
      float t = w[dd * KCODES + g];
      s = fmaf(t, t, s);
    }
    wsq[g] = s;
  }
  if (g == 0) *loss_out = 0.f;             // d_out is poisoned each launch
}

__global__ __launch_bounds__(512, 8)
void vq_main(const float* __restrict__ x_in, const float* __restrict__ w,
             const float* __restrict__ wT, const float* __restrict__ wsq,
             float* __restrict__ out_q, float* __restrict__ out_idx,
             float* __restrict__ loss_out) {
  __shared__ float xs[DDIM][65];                // transposed x tile (+1 pad)
  __shared__ unsigned long long sm_key[8][64];  // per-wave candidate keys
  __shared__ unsigned int sm_idx[64];
  __shared__ float sm_sx[64];
  __shared__ float sm_loss[64];

  const int t = threadIdx.x;
  const int pb = blockIdx.x;                              // 1024 blocks, 64 pts
  const int wv = __builtin_amdgcn_readfirstlane(t >> 6);  // wave id 0..7 (SGPR)
  const int lane = t & 63;                                // lane = point id

  // ---- stage: 64 pts x 64 d, coalesced read, transpose into LDS ----
  {
    const float4* src = (const float4*)(x_in + (size_t)pb * 4096);
#pragma unroll
    for (int i = 0; i < 2; ++i) {
      int e4 = i * 512 + t;              // float4 index 0..1023
      float4 v = src[e4];                // coalesced 16B/lane
      int e = e4 << 2;
      int pt = e >> 6, d = e & 63;
      xs[d][pt] = v.x; xs[d + 1][pt] = v.y;
      xs[d + 2][pt] = v.z; xs[d + 3][pt] = v.w;
    }
  }
  __syncthreads();

  const int kbase = wv << 6;             // this wave's 64-code slice

  float best = 3.0e38f;
  int bidx = 0;
  float sx = 0.f;

#pragma unroll 1
  for (int kb = 0; kb < 2; ++kb) {       // 2 x 32-code windows (R6 codegen)
    const int k0 = kbase + (kb << 5);
    const float* wp = w + k0;            // SGPR-rooted -> s_load promotion
    float acc[32];
#pragma unroll
    for (int c = 0; c < 32; ++c) acc[c] = 0.f;

#pragma unroll 1
    for (int d8 = 0; d8 < 8; ++d8) {
      float xv[8];
#pragma unroll
      for (int dd = 0; dd < 8; ++dd)
        xv[dd] = xs[(d8 << 3) + dd][lane];        // conflict-free ds_read
      if (wv == 0 && kb == 0) {  // wave-uniform: ||x||^2 once per point
#pragma unroll
        for (int dd = 0; dd < 8; ++dd) sx = fmaf(xv[dd], xv[dd], sx);
      }
#pragma unroll
      for (int dd = 0; dd < 8; ++dd) {
        const float* wd = wp + (((d8 << 3) + dd) << 9);  // w[d][k0..k0+31]
#pragma unroll
        for (int c = 0; c < 32; ++c)
          acc[c] = fmaf(wd[c], xv[dd], acc[c]);  // sgpr * vgpr fmac
      }
    }
#pragma unroll
    for (int c = 0; c < 32; ++c) {
      float dist = fmaf(acc[c], -2.0f, wsq[k0 + c]);
      if (dist < best) { best = dist; bidx = k0 + c; }  // strict <: first-min
    }
  }

  // sortable-float pack, idx in low bits -> exact ties pick lowest index
  unsigned int ub = __float_as_uint(best);
  ub = (ub & 0x80000000u) ? ~ub : (ub | 0x80000000u);
  sm_key[wv][lane] =
      ((unsigned long long)ub << 32) | (unsigned long long)(unsigned int)bidx;
  if (wv == 0) sm_sx[lane] = sx;
  __syncthreads();

  // ---- merge the 8 per-wave candidates for each of the 64 points ----
  if (t < 64) {
    unsigned long long k = sm_key[0][t];
#pragma unroll
    for (int wi = 1; wi < 8; ++wi) {
      unsigned long long k2 = sm_key[wi][t];
      k = k2 < k ? k2 : k;
    }
    unsigned int idx = (unsigned int)k;
    sm_idx[t] = idx;
    out_idx[((size_t)pb << 6) + t] = (float)idx;
    unsigned int u = (unsigned int)(k >> 32);
    u = (u & 0x80000000u) ? (u & 0x7FFFFFFFu) : ~u;
    // ||x-q||^2 = ||x||^2 + (||q||^2 - 2 x.q), pre-scaled by 1.25/(N*D)
    sm_loss[t] = (__uint_as_float(u) + sm_sx[t]) * (1.25f / 4194304.0f);
  }
  __syncthreads();

  // ---- epilogue: gather code rows, coalesced 64x64 out tile ----
  float4* dst = (float4*)(out_q + (size_t)pb * 4096);
#pragma unroll
  for (int i = 0; i < 2; ++i) {
    int e4 = i * 512 + t;
    int p2 = e4 >> 4, d4 = e4 & 15;
    unsigned int idx = sm_idx[p2];                            // LDS broadcast
    dst[e4] = ((const float4*)(wT + (size_t)idx * DDIM))[d4]; // L2-hot
  }

  // block loss partial -> single atomic (1024 adds total)
  if (t < 64) {
    float s = sm_loss[t];
#pragma unroll
    for (int off = 32; off > 0; off >>= 1) s += __shfl_down(s, off);
    if (t == 0) atomicAdd(loss_out, s);
  }
}

extern "C" void kernel_launch(void* const* d_in, const int* in_sizes, int n_in,
                              void* d_out, int out_size, void* d_ws, size_t ws_size,
                              hipStream_t stream) {
  const float* x = (const float*)d_in[0];  // (64,32,32,64) fp32
  const float* w = (const float*)d_in[1];  // (64,512) fp32

  char* ws = (char*)d_ws;
  float* wT = (float*)(ws);
  float* wsq = (float*)(ws + 131072);

  float* out_q = (float*)d_out;            // 4194304 floats
  float* out_idx = out_q + 4194304;        // 65536 floats (indices)
  float* loss_out = out_q + 4259840;       // 1 float

  vq_prep<<<128, 256, 0, stream>>>(w, wT, wsq, loss_out);
  vq_main<<<1024, 512, 0, stream>>>(x, w, wT, wsq, out_q, out_idx, loss_out);
}